// Round 2
// baseline (4183.961 us; speedup 1.0000x reference)
//
#include <hip/hip_runtime.h>
#include <stdint.h>

typedef unsigned int uint32;
typedef unsigned long long uint64;

#define NPIX      10000
#define NCH       1024
#define NANCH     90000
#define PRE_TOPK  6000
#define POST_TOPK 300
#define SORT_N    8192
#define NWORDS    94          // ceil(6000/64)
#define SUP_ROWS  6016
#define BBOX_CLIP_F 4.135166556742356f

__device__ __forceinline__ uint64 shfl64(uint64 v, int lane) {
    int lo = __shfl((int)(uint32)v, lane);
    int hi = __shfl((int)(uint32)(v >> 32), lane);
    return ((uint64)(uint32)hi << 32) | (uint32)lo;
}

// ---------------- fallback: zero the output (diagnostic clean-fail) ----------------
__global__ __launch_bounds__(256) void zero_out(float* __restrict__ out, int n) {
    int i = blockIdx.x * 256 + threadIdx.x;
    if (i < n) out[i] = 0.f;
}

// ---------------- repack conv_w [co][ci][3][3] -> W2 [kk][ci][co] ----------------
__global__ __launch_bounds__(256) void repack_w(const float* __restrict__ w, float* __restrict__ W2) {
    int kk = blockIdx.x;          // 0..8
    int tile = blockIdx.y;        // 0..255
    int tci = (tile & 15) << 6;
    int tco = (tile >> 4) << 6;
    __shared__ float lds[64][65];
    int t = threadIdx.x;
    int c0 = t & 63;
    int r0 = t >> 6;              // 0..3
#pragma unroll
    for (int r = 0; r < 16; ++r) {
        int col = r0 + (r << 2);  // co offset 0..63
        int ci = tci + c0;
        int co = tco + col;
        lds[col][c0] = w[((size_t)co * 1024 + ci) * 9 + kk];
    }
    __syncthreads();
#pragma unroll
    for (int r = 0; r < 16; ++r) {
        int row = r0 + (r << 2);  // ci offset
        int ci = tci + row;
        int co = tco + c0;
        W2[((size_t)kk * 1024 + ci) * 1024 + co] = lds[c0][row];
    }
}

// ---------------- 3x3 conv as fp32 GEMM: feats[co][p] = relu(b + sum) ----------------
__global__ __launch_bounds__(256) void conv3x3(const float* __restrict__ fm,
        const float* __restrict__ W2, const float* __restrict__ bias,
        float* __restrict__ feats) {
    const int n0 = blockIdx.x << 6;   // pixel tile (157)
    const int m0 = blockIdx.y << 6;   // c_out tile (16)
    const int t = threadIdx.x;
    __shared__ float Wt[32][68];
    __shared__ float Xt[32][68];
    const int lr = t >> 3;            // 0..31
    const int lc = (t & 7) << 3;      // 0..63 step 8
    int pyv[8], pxv[8];
#pragma unroll
    for (int j = 0; j < 8; ++j) {
        int p = n0 + lc + j;
        int y = p / 100;
        int x = p - y * 100;
        pyv[j] = (p < NPIX) ? y : -1000;
        pxv[j] = x;
    }
    const int tm = (t >> 4) << 2;
    const int tn = (t & 15) << 2;
    float acc[4][4] = {};
    for (int kk = 0; kk < 9; ++kk) {
        const int ky = kk / 3 - 1, kx = kk % 3 - 1;
        const float* W2k = W2 + (size_t)kk * 1024 * 1024 + m0 + lc;
        for (int ci0 = 0; ci0 < 1024; ci0 += 32) {
            __syncthreads();
            const float* wsrc = W2k + (size_t)(ci0 + lr) * 1024;
            float4 w0 = *(const float4*)(wsrc);
            float4 w1 = *(const float4*)(wsrc + 4);
            const float* fmc = fm + (size_t)(ci0 + lr) * NPIX;
            float xv[8];
#pragma unroll
            for (int j = 0; j < 8; ++j) {
                int yy = pyv[j] + ky;
                int xx = pxv[j] + kx;
                bool ok = (yy >= 0) & (yy < 100) & (xx >= 0) & (xx < 100);
                xv[j] = ok ? fmc[yy * 100 + xx] : 0.f;
            }
            *(float4*)&Wt[lr][lc] = w0;
            *(float4*)&Wt[lr][lc + 4] = w1;
            *(float4*)&Xt[lr][lc]     = make_float4(xv[0], xv[1], xv[2], xv[3]);
            *(float4*)&Xt[lr][lc + 4] = make_float4(xv[4], xv[5], xv[6], xv[7]);
            __syncthreads();
#pragma unroll
            for (int k = 0; k < 32; ++k) {
                const float4 wv = *(const float4*)&Wt[k][tm];
                const float4 xq = *(const float4*)&Xt[k][tn];
                float wr[4] = {wv.x, wv.y, wv.z, wv.w};
                float xr[4] = {xq.x, xq.y, xq.z, xq.w};
#pragma unroll
                for (int i = 0; i < 4; ++i)
#pragma unroll
                    for (int j = 0; j < 4; ++j)
                        acc[i][j] = fmaf(wr[i], xr[j], acc[i][j]);
            }
        }
    }
#pragma unroll
    for (int i = 0; i < 4; ++i) {
        int m = m0 + tm + i;
        float b = bias[m];
#pragma unroll
        for (int j = 0; j < 4; ++j) {
            int p = n0 + tn + j;
            if (p < NPIX) feats[(size_t)m * NPIX + p] = fmaxf(acc[i][j] + b, 0.f);
        }
    }
}

// ---------------- 1x1 heads: obj->prob->sortkey, reg->regflat ----------------
__global__ __launch_bounds__(256) void heads(const float* __restrict__ feats,
        const float* __restrict__ objw, const float* __restrict__ objb,
        const float* __restrict__ regw, const float* __restrict__ regb,
        uint32* __restrict__ keys32, float* __restrict__ regflat) {
    int p0 = blockIdx.x << 6;
    int t = threadIdx.x;
    int pl = t & 63;
    int g = t >> 6;     // 0..3
    __shared__ float fts[64][65];
    __shared__ float wl[48][64];
    float acc[12] = {};
    for (int c0 = 0; c0 < 1024; c0 += 64) {
        __syncthreads();
#pragma unroll
        for (int r = 0; r < 16; ++r) {
            int cc = g + (r << 2);
            int p = p0 + pl;
            fts[cc][pl] = (p < NPIX) ? feats[(size_t)(c0 + cc) * NPIX + p] : 0.f;
        }
#pragma unroll
        for (int i = 0; i < 12; ++i) {
            int flat = (i << 8) + t;     // < 3072
            int o = flat >> 6;
            int cc = flat & 63;
            float v = 0.f;
            if (o < 9) v = objw[o * 1024 + c0 + cc];
            else if (o < 45) v = regw[(o - 9) * 1024 + c0 + cc];
            wl[o][cc] = v;
        }
        __syncthreads();
#pragma unroll 16
        for (int cc = 0; cc < 64; ++cc) {
            float v = fts[cc][pl];
#pragma unroll
            for (int i = 0; i < 12; ++i)
                acc[i] = fmaf(v, wl[g + (i << 2)][cc], acc[i]);
        }
    }
    int p = p0 + pl;
    if (p < NPIX) {
#pragma unroll
        for (int i = 0; i < 12; ++i) {
            int o = g + (i << 2);
            if (o < 9) {
                float logit = acc[i] + objb[o];
                float prob = 1.f / (1.f + expf(-logit));
                keys32[p * 9 + o] = 0xFFFFFFFFu - __float_as_uint(prob);
            } else if (o < 45) {
                int ch = o - 9;
                float v = acc[i] + regb[ch];
                int a = ch >> 2, d = ch & 3;
                regflat[((size_t)p * 9 + a) * 4 + d] = v;
            }
        }
    }
}

// ---------------- radix select: T = 6000th smallest key ----------------
__global__ __launch_bounds__(1024) void radix_select(const uint32* __restrict__ keys, uint32* __restrict__ meta) {
    __shared__ uint32 hist[256];
    __shared__ uint32 sPrefix, sK;
    int t = threadIdx.x;
    if (t == 0) { sPrefix = 0; sK = PRE_TOPK; }
    for (int pass = 0; pass < 4; ++pass) {
        int shift = 24 - pass * 8;
        uint32 kmask = pass ? (0xFFFFFFFFu << (32 - 8 * pass)) : 0u;
        if (t < 256) hist[t] = 0;
        __syncthreads();
        uint32 pref = sPrefix;
        for (int i = t; i < NANCH; i += 1024) {
            uint32 k = keys[i];
            if ((k & kmask) == pref) atomicAdd(&hist[(k >> shift) & 255], 1u);
        }
        __syncthreads();
        if (t == 0) {
            uint32 cum = 0, K = sK;
            for (int b = 0; b < 256; ++b) {
                uint32 c = hist[b];
                if (cum + c >= K) { sPrefix = pref | ((uint32)b << shift); sK = K - cum; break; }
                cum += c;
            }
        }
        __syncthreads();
    }
    if (t == 0) meta[0] = sPrefix;
}

// ---------------- compact all keys <= T ----------------
__global__ __launch_bounds__(256) void compact_k(const uint32* __restrict__ keys, const uint32* __restrict__ meta,
        uint32* __restrict__ cnt, uint64* __restrict__ sel) {
    int i = blockIdx.x * 256 + threadIdx.x;
    if (i >= NANCH) return;
    uint32 T = meta[0];
    uint32 k = keys[i];
    if (k <= T) {
        uint32 pos = atomicAdd(cnt, 1u);
        if (pos < SORT_N) sel[pos] = ((uint64)k << 32) | (uint32)i;
    }
}

// ---------------- single-block bitonic sort of 8192 (key32|idx) ----------------
__global__ __launch_bounds__(1024) void bitonic_sort(const uint32* __restrict__ meta, const uint64* __restrict__ sel,
        uint64* __restrict__ sorted) {
    __shared__ uint64 arr[SORT_N];
    int t = threadIdx.x;
    uint32 cnt = meta[1]; if (cnt > SORT_N) cnt = SORT_N;
    for (int i = t; i < SORT_N; i += 1024) arr[i] = (i < (int)cnt) ? sel[i] : 0xFFFFFFFFFFFFFFFFull;
    __syncthreads();
    for (unsigned k = 2; k <= SORT_N; k <<= 1) {
        for (unsigned j = k >> 1; j > 0; j >>= 1) {
#pragma unroll 1
            for (int s = 0; s < SORT_N / 1024; ++s) {
                unsigned i = s * 1024 + t;
                unsigned l = i ^ j;
                if (l > i) {
                    uint64 a = arr[i], b = arr[l];
                    bool up = ((i & k) == 0);
                    if ((a > b) == up) { arr[i] = b; arr[l] = a; }
                }
            }
            __syncthreads();
        }
    }
    for (int i = t; i < PRE_TOPK; i += 1024) sorted[i] = arr[i];
}

// ---------------- decode + clip + min-size for top 6000 ----------------
__global__ __launch_bounds__(256) void decode_k(const uint64* __restrict__ sorted,
        const float* __restrict__ regflat,
        float4* __restrict__ boxes, float* __restrict__ probv, uint32* __restrict__ valid) {
    int i = blockIdx.x * 256 + threadIdx.x;
    if (i >= PRE_TOPK) return;
    uint64 v = sorted[i];
    uint32 idx = (uint32)v;
    uint32 key = (uint32)(v >> 32);
    float prob = __uint_as_float(0xFFFFFFFFu - key);
    int a = idx % 9;
    int p = idx / 9;
    int y = p / 100;
    int x = p - y * 100;
    const float ratios[3] = {0.5f, 1.0f, 2.0f};
    const float scales[3] = {128.f, 256.f, 512.f};
    float ratio = ratios[a / 3];
    float scale = scales[a % 3];
    float h_r = sqrtf(ratio);
    float w_r = 1.0f / h_r;
    float wsz = w_r * scale;
    float hsz = h_r * scale;
    float sx = 16.f * (float)x;
    float sy = 16.f * (float)y;
    float ax1 = sx - wsz * 0.5f;
    float ay1 = sy - hsz * 0.5f;
    float ax2 = sx + wsz * 0.5f;
    float ay2 = sy + hsz * 0.5f;
    float wa = ax2 - ax1;
    float ha = ay2 - ay1;
    float cxa = ax1 + 0.5f * wa;
    float cya = ay1 + 0.5f * ha;
    float dx = regflat[(size_t)idx * 4 + 0];
    float dy = regflat[(size_t)idx * 4 + 1];
    float dw = fminf(regflat[(size_t)idx * 4 + 2], BBOX_CLIP_F);
    float dh = fminf(regflat[(size_t)idx * 4 + 3], BBOX_CLIP_F);
    float cx = dx * wa + cxa;
    float cy = dy * ha + cya;
    float w = expf(dw) * wa;
    float h = expf(dh) * ha;
    float x1 = cx - 0.5f * w, y1 = cy - 0.5f * h, x2 = cx + 0.5f * w, y2 = cy + 0.5f * h;
    x1 = fminf(fmaxf(x1, 0.f), 1600.f);
    y1 = fminf(fmaxf(y1, 0.f), 1600.f);
    x2 = fminf(fmaxf(x2, 0.f), 1600.f);
    y2 = fminf(fmaxf(y2, 0.f), 1600.f);
    boxes[i] = make_float4(x1, y1, x2, y2);
    probv[i] = prob;
    valid[i] = (((x2 - x1) >= 16.f) & ((y2 - y1) >= 16.f)) ? 1u : 0u;
}

// ---------------- NMS suppression bitmask (j > i, iou > 0.7) ----------------
__global__ __launch_bounds__(64) void nms_pairs(const float4* __restrict__ boxes, uint64* __restrict__ sup) {
    int bi = blockIdx.y, bj = blockIdx.x;
    int t = threadIdx.x;
    int i = bi * 64 + t;
    if (bj < bi) { if (i < SUP_ROWS) sup[(size_t)i * NWORDS + bj] = 0; return; }
    __shared__ float4 bx[64];
    __shared__ float ab[64];
    int j0 = bj * 64;
    float4 bb = (j0 + t < PRE_TOPK) ? boxes[j0 + t] : make_float4(0, 0, 0, 0);
    bx[t] = bb;
    ab[t] = (bb.z - bb.x) * (bb.w - bb.y);
    __syncthreads();
    uint64 bits = 0;
    if (i < PRE_TOPK) {
        float4 ba = boxes[i];
        float aa = (ba.z - ba.x) * (ba.w - ba.y);
        for (int jj = 0; jj < 64; ++jj) {
            int j = j0 + jj;
            if (j > i && j < PRE_TOPK) {
                float4 bv = bx[jj];
                float ltx = fmaxf(ba.x, bv.x);
                float lty = fmaxf(ba.y, bv.y);
                float rbx = fminf(ba.z, bv.z);
                float rby = fminf(ba.w, bv.w);
                float wv = fmaxf(rbx - ltx, 0.f);
                float hv = fmaxf(rby - lty, 0.f);
                float inter = wv * hv;
                float iou = inter / (aa + ab[jj] - inter);
                if (iou > 0.7f) bits |= (1ull << jj);
            }
        }
    }
    if (i < SUP_ROWS) sup[(size_t)i * NWORDS + bj] = bits;
}

// ---------------- sequential greedy scan, early-exit at 300 kept ----------------
__global__ __launch_bounds__(64) void nms_scan(const uint32* __restrict__ valid, const uint64* __restrict__ sup,
        uint32* __restrict__ keeplist, uint32* __restrict__ kcount) {
    int l = threadIdx.x;
    __shared__ uint64 srow[64][95];
    uint64 r0 = 0, r1 = 0;
    for (int b = 0; b < 64; ++b) {
        int idx = l * 64 + b;
        if (idx < PRE_TOPK && valid[idx]) r0 |= (1ull << b);
    }
    if (l < NWORDS - 64) {
        int base = (64 + l) * 64;
        for (int b = 0; b < 64; ++b) {
            int idx = base + b;
            if (idx < PRE_TOPK && valid[idx]) r1 |= (1ull << b);
        }
    }
    int outc = 0;
    bool done = false;
    for (int c = 0; c < NWORDS && !done; ++c) {
        __syncthreads();
        for (int rr = 0; rr < 64; ++rr) {
            int row = c * 64 + rr;
            srow[rr][l] = sup[(size_t)row * NWORDS + l];
            if (l < NWORDS - 64) srow[rr][64 + l] = sup[(size_t)row * NWORDS + 64 + l];
        }
        __syncthreads();
        for (int ii = 0; ii < 64; ++ii) {
            int i = c * 64 + ii;
            if (i >= PRE_TOPK) break;
            uint64 kw = (c < 64) ? shfl64(r0, c) : shfl64(r1, c - 64);
            if ((kw >> ii) & 1ull) {
                if (l == 0) keeplist[outc] = (uint32)i;
                ++outc;
                if (outc >= POST_TOPK) { done = true; break; }
                r0 &= ~srow[ii][l];
                if (l < NWORDS - 64) r1 &= ~srow[ii][64 + l];
            }
        }
    }
    if (l == 0) *kcount = (uint32)outc;
}

// ---------------- final gather: first 300 kept ----------------
__global__ __launch_bounds__(512) void finalize_k(const uint32* __restrict__ keeplist, const uint32* __restrict__ kcount,
        const float4* __restrict__ boxes, const float* __restrict__ probv, float* __restrict__ out) {
    int t = threadIdx.x;
    if (t < POST_TOPK) {
        uint32 kc = *kcount;
        if (t < (int)kc) {
            int i = keeplist[t];
            float4 b = boxes[i];
            out[t * 4 + 0] = b.x; out[t * 4 + 1] = b.y; out[t * 4 + 2] = b.z; out[t * 4 + 3] = b.w;
            out[1200 + t] = probv[i];
        } else {
            out[t * 4 + 0] = 0.f; out[t * 4 + 1] = 0.f; out[t * 4 + 2] = 0.f; out[t * 4 + 3] = 0.f;
            out[1200 + t] = 0.f;
        }
    }
}

extern "C" void kernel_launch(void* const* d_in, const int* in_sizes, int n_in,
                              void* d_out, int out_size, void* d_ws, size_t ws_size,
                              hipStream_t stream) {
    const float* fm = (const float*)d_in[1];
    const float* cw = (const float*)d_in[2];
    const float* cb = (const float*)d_in[3];
    const float* ow = (const float*)d_in[4];
    const float* ob = (const float*)d_in[5];
    const float* rw = (const float*)d_in[6];
    const float* rb = (const float*)d_in[7];
    float* out = (float*)d_out;

    uint8_t* base = (uint8_t*)d_ws;
    size_t off = 0;
    auto alloc = [&](size_t bytes) -> void* {
        void* p = base + off;
        off = (off + bytes + 255) & ~(size_t)255;
        return p;
    };
    // --- persistent region ---
    float* feats    = (float*)alloc((size_t)NCH * NPIX * 4);          // 40.96 MB
    uint32* meta    = (uint32*)alloc(64);                             // [0]=T, [1]=cnt
    uint32* keepl   = (uint32*)alloc(POST_TOPK * 4);
    uint32* kcount  = (uint32*)alloc(64);
    // --- union region: W2 (used only by repack_w + conv3x3) overlaps all
    //     post-conv buffers (first written by heads, after conv3x3 completes) ---
    size_t ubase = off;
    float* W2       = (float*)alloc((size_t)9 * 1024 * 1024 * 4);     // 36 MB
    size_t endA = off;
    off = ubase;                                                      // rewind: alias
    uint32* keys    = (uint32*)alloc((size_t)NANCH * 4);
    float* regflat  = (float*)alloc((size_t)NANCH * 4 * 4);
    uint64* sel     = (uint64*)alloc((size_t)SORT_N * 8);
    uint64* sorted  = (uint64*)alloc((size_t)PRE_TOPK * 8);
    float4* boxes   = (float4*)alloc((size_t)PRE_TOPK * 16);
    float* probv    = (float*)alloc((size_t)PRE_TOPK * 4);
    uint32* validb  = (uint32*)alloc((size_t)PRE_TOPK * 4);
    uint64* sup     = (uint64*)alloc((size_t)SUP_ROWS * NWORDS * 8);
    size_t endB = off;
    size_t needed = (endA > endB) ? endA : endB;

    if (needed > ws_size) {
        // Workspace too small: clean, deterministic failure instead of OOB writes.
        zero_out<<<(out_size + 255) / 256, 256, 0, stream>>>(out, out_size);
        return;
    }

    hipMemsetAsync(meta, 0, 64, stream);

    repack_w<<<dim3(9, 256), 256, 0, stream>>>(cw, W2);
    conv3x3<<<dim3(157, 16), 256, 0, stream>>>(fm, W2, cb, feats);
    heads<<<157, 256, 0, stream>>>(feats, ow, ob, rw, rb, keys, regflat);
    radix_select<<<1, 1024, 0, stream>>>(keys, meta);
    compact_k<<<(NANCH + 255) / 256, 256, 0, stream>>>(keys, meta, meta + 1, sel);
    bitonic_sort<<<1, 1024, 0, stream>>>(meta, sel, sorted);
    decode_k<<<(PRE_TOPK + 255) / 256, 256, 0, stream>>>(sorted, regflat, boxes, probv, validb);
    nms_pairs<<<dim3(NWORDS, NWORDS), 64, 0, stream>>>(boxes, sup);
    nms_scan<<<1, 64, 0, stream>>>(validb, sup, keepl, kcount);
    finalize_k<<<1, 512, 0, stream>>>(keepl, kcount, boxes, probv, out);
}

// Round 3
// 3706.714 us; speedup vs baseline: 1.1288x; 1.1288x over previous
//
#include <hip/hip_runtime.h>
#include <stdint.h>

typedef unsigned int uint32;
typedef unsigned long long uint64;

#define NPIX      10000
#define NCH       1024
#define NANCH     90000
#define PRE_TOPK  6000
#define POST_TOPK 300
#define SORT_N    8192
#define NWORDS    94          // ceil(6000/64)
#define SUP_ROWS  6016
#define BBOX_CLIP_F 4.135166556742356f

// conv_sw geometry
#define TILE_H   8
#define TILE_W   16
#define HALO_H   10
#define HALO_W   18
#define HALO_WP  20          // padded row stride (floats): 2-way bank aliasing only (free)
#define CICHUNK  16
#define CO_PER_WAVE 32

__device__ __forceinline__ uint64 shfl64(uint64 v, int lane) {
    int lo = __shfl((int)(uint32)v, lane);
    int hi = __shfl((int)(uint32)(v >> 32), lane);
    return ((uint64)(uint32)hi << 32) | (uint32)lo;
}

// ---------------- fallback: zero the output (diagnostic clean-fail) ----------------
__global__ __launch_bounds__(256) void zero_out(float* __restrict__ out, int n) {
    int i = blockIdx.x * 256 + threadIdx.x;
    if (i < n) out[i] = 0.f;
}

// ---------------- repack conv_w [co][ci][3][3] -> W2 [kk][ci][co] ----------------
__global__ __launch_bounds__(256) void repack_w(const float* __restrict__ w, float* __restrict__ W2) {
    int kk = blockIdx.x;          // 0..8
    int tile = blockIdx.y;        // 0..255
    int tci = (tile & 15) << 6;
    int tco = (tile >> 4) << 6;
    __shared__ float lds[64][65];
    int t = threadIdx.x;
    int c0 = t & 63;
    int r0 = t >> 6;              // 0..3
#pragma unroll
    for (int r = 0; r < 16; ++r) {
        int col = r0 + (r << 2);  // co offset 0..63
        int ci = tci + c0;
        int co = tco + col;
        lds[col][c0] = w[((size_t)co * 1024 + ci) * 9 + kk];
    }
    __syncthreads();
#pragma unroll
    for (int r = 0; r < 16; ++r) {
        int row = r0 + (r << 2);  // ci offset
        int ci = tci + row;
        int co = tco + c0;
        W2[((size_t)kk * 1024 + ci) * 1024 + co] = lds[c0][row];
    }
}

// ---------------- 3x3 conv: scalar-weight outer product ----------------
// Grid: (91 pixel tiles, 8 co tiles), 256 threads = 4 waves.
// Lane owns 2 pixels (8x8 sub-tile, px offset +8 cols); wave owns 32 co.
// Weights fetched via wave-uniform address -> s_load (scalar pipe), FMAs use
// SGPR weight operand: per (ci,kk) step = 2 ds_read_b32 + 64 v_fmac_f32.
__global__ __launch_bounds__(256) void conv_sw(const float* __restrict__ fm,
        const float* __restrict__ W2, const float* __restrict__ bias,
        float* __restrict__ feats) {
    __shared__ float xt[CICHUNK][HALO_H][HALO_WP];
    const int t = threadIdx.x;
    const int lane = t & 63;
    const int wv = t >> 6;
    const int tile = blockIdx.x;
    const int tx0 = (tile % 7) * TILE_W;
    const int ty0 = (tile / 7) * TILE_H;
    const int co0 = __builtin_amdgcn_readfirstlane((blockIdx.y << 7) + (wv << 5));
    const int ly = lane >> 3, lx = lane & 7;

    float acc0[CO_PER_WAVE] = {};
    float acc1[CO_PER_WAVE] = {};

#pragma unroll 1
    for (int c0 = 0; c0 < NCH; c0 += CICHUNK) {
        __syncthreads();
        // stage halo'd fm chunk: CICHUNK x 10 x 18 (zero-padded OOB)
        for (int i = t; i < CICHUNK * HALO_H * HALO_W; i += 256) {
            int ci = i / (HALO_H * HALO_W);
            int rem = i - ci * (HALO_H * HALO_W);
            int hy = rem / HALO_W;
            int hx = rem - hy * HALO_W;
            int gy = ty0 - 1 + hy;
            int gx = tx0 - 1 + hx;
            bool ok = (gy >= 0) & (gy < 100) & (gx >= 0) & (gx < 100);
            xt[ci][hy][hx] = ok ? fm[(size_t)(c0 + ci) * NPIX + gy * 100 + gx] : 0.f;
        }
        __syncthreads();
#pragma unroll 1
        for (int ci = 0; ci < CICHUNK; ++ci) {
#pragma unroll
            for (int kk = 0; kk < 9; ++kk) {
                const int ky = kk / 3, kx2 = kk % 3;
                float x0v = xt[ci][ly + ky][lx + kx2];
                float x1v = xt[ci][ly + ky][lx + 8 + kx2];
                const float* wp = W2 + ((((size_t)kk << 10) + (size_t)(c0 + ci)) << 10) + co0;
#pragma unroll
                for (int c = 0; c < CO_PER_WAVE; ++c) {
                    float wgt = wp[c];            // wave-uniform -> s_load, SGPR operand
                    acc0[c] = fmaf(wgt, x0v, acc0[c]);
                    acc1[c] = fmaf(wgt, x1v, acc1[c]);
                }
            }
        }
    }

    const int gy = ty0 + ly;
    const int gx0 = tx0 + lx;
    const int gx1 = tx0 + 8 + lx;
    const bool oky = gy < 100;
#pragma unroll
    for (int c = 0; c < CO_PER_WAVE; ++c) {
        float b = bias[co0 + c];
        if (oky && (gx0 < 100)) feats[(size_t)(co0 + c) * NPIX + gy * 100 + gx0] = fmaxf(acc0[c] + b, 0.f);
        if (oky && (gx1 < 100)) feats[(size_t)(co0 + c) * NPIX + gy * 100 + gx1] = fmaxf(acc1[c] + b, 0.f);
    }
}

// ---------------- 1x1 heads: obj->prob->sortkey, reg->regflat ----------------
__global__ __launch_bounds__(256) void heads(const float* __restrict__ feats,
        const float* __restrict__ objw, const float* __restrict__ objb,
        const float* __restrict__ regw, const float* __restrict__ regb,
        uint32* __restrict__ keys32, float* __restrict__ regflat) {
    int p0 = blockIdx.x << 6;
    int t = threadIdx.x;
    int pl = t & 63;
    int g = t >> 6;     // 0..3
    __shared__ float fts[64][65];
    __shared__ float wl[48][64];
    float acc[12] = {};
    for (int c0 = 0; c0 < 1024; c0 += 64) {
        __syncthreads();
#pragma unroll
        for (int r = 0; r < 16; ++r) {
            int cc = g + (r << 2);
            int p = p0 + pl;
            fts[cc][pl] = (p < NPIX) ? feats[(size_t)(c0 + cc) * NPIX + p] : 0.f;
        }
#pragma unroll
        for (int i = 0; i < 12; ++i) {
            int flat = (i << 8) + t;     // < 3072
            int o = flat >> 6;
            int cc = flat & 63;
            float v = 0.f;
            if (o < 9) v = objw[o * 1024 + c0 + cc];
            else if (o < 45) v = regw[(o - 9) * 1024 + c0 + cc];
            wl[o][cc] = v;
        }
        __syncthreads();
#pragma unroll 16
        for (int cc = 0; cc < 64; ++cc) {
            float v = fts[cc][pl];
#pragma unroll
            for (int i = 0; i < 12; ++i)
                acc[i] = fmaf(v, wl[g + (i << 2)][cc], acc[i]);
        }
    }
    int p = p0 + pl;
    if (p < NPIX) {
#pragma unroll
        for (int i = 0; i < 12; ++i) {
            int o = g + (i << 2);
            if (o < 9) {
                float logit = acc[i] + objb[o];
                float prob = 1.f / (1.f + expf(-logit));
                keys32[p * 9 + o] = 0xFFFFFFFFu - __float_as_uint(prob);
            } else if (o < 45) {
                int ch = o - 9;
                float v = acc[i] + regb[ch];
                int a = ch >> 2, d = ch & 3;
                regflat[((size_t)p * 9 + a) * 4 + d] = v;
            }
        }
    }
}

// ---------------- radix select: T = 6000th smallest key ----------------
__global__ __launch_bounds__(1024) void radix_select(const uint32* __restrict__ keys, uint32* __restrict__ meta) {
    __shared__ uint32 hist[256];
    __shared__ uint32 sPrefix, sK;
    int t = threadIdx.x;
    if (t == 0) { sPrefix = 0; sK = PRE_TOPK; }
    for (int pass = 0; pass < 4; ++pass) {
        int shift = 24 - pass * 8;
        uint32 kmask = pass ? (0xFFFFFFFFu << (32 - 8 * pass)) : 0u;
        if (t < 256) hist[t] = 0;
        __syncthreads();
        uint32 pref = sPrefix;
        for (int i = t; i < NANCH; i += 1024) {
            uint32 k = keys[i];
            if ((k & kmask) == pref) atomicAdd(&hist[(k >> shift) & 255], 1u);
        }
        __syncthreads();
        if (t == 0) {
            uint32 cum = 0, K = sK;
            for (int b = 0; b < 256; ++b) {
                uint32 c = hist[b];
                if (cum + c >= K) { sPrefix = pref | ((uint32)b << shift); sK = K - cum; break; }
                cum += c;
            }
        }
        __syncthreads();
    }
    if (t == 0) meta[0] = sPrefix;
}

// ---------------- compact all keys <= T ----------------
__global__ __launch_bounds__(256) void compact_k(const uint32* __restrict__ keys, const uint32* __restrict__ meta,
        uint32* __restrict__ cnt, uint64* __restrict__ sel) {
    int i = blockIdx.x * 256 + threadIdx.x;
    if (i >= NANCH) return;
    uint32 T = meta[0];
    uint32 k = keys[i];
    if (k <= T) {
        uint32 pos = atomicAdd(cnt, 1u);
        if (pos < SORT_N) sel[pos] = ((uint64)k << 32) | (uint32)i;
    }
}

// ---------------- single-block bitonic sort of 8192 (key32|idx) ----------------
__global__ __launch_bounds__(1024) void bitonic_sort(const uint32* __restrict__ meta, const uint64* __restrict__ sel,
        uint64* __restrict__ sorted) {
    __shared__ uint64 arr[SORT_N];
    int t = threadIdx.x;
    uint32 cnt = meta[1]; if (cnt > SORT_N) cnt = SORT_N;
    for (int i = t; i < SORT_N; i += 1024) arr[i] = (i < (int)cnt) ? sel[i] : 0xFFFFFFFFFFFFFFFFull;
    __syncthreads();
    for (unsigned k = 2; k <= SORT_N; k <<= 1) {
        for (unsigned j = k >> 1; j > 0; j >>= 1) {
#pragma unroll 1
            for (int s = 0; s < SORT_N / 1024; ++s) {
                unsigned i = s * 1024 + t;
                unsigned l = i ^ j;
                if (l > i) {
                    uint64 a = arr[i], b = arr[l];
                    bool up = ((i & k) == 0);
                    if ((a > b) == up) { arr[i] = b; arr[l] = a; }
                }
            }
            __syncthreads();
        }
    }
    for (int i = t; i < PRE_TOPK; i += 1024) sorted[i] = arr[i];
}

// ---------------- decode + clip + min-size for top 6000 ----------------
__global__ __launch_bounds__(256) void decode_k(const uint64* __restrict__ sorted,
        const float* __restrict__ regflat,
        float4* __restrict__ boxes, float* __restrict__ probv, uint32* __restrict__ valid) {
    int i = blockIdx.x * 256 + threadIdx.x;
    if (i >= PRE_TOPK) return;
    uint64 v = sorted[i];
    uint32 idx = (uint32)v;
    uint32 key = (uint32)(v >> 32);
    float prob = __uint_as_float(0xFFFFFFFFu - key);
    int a = idx % 9;
    int p = idx / 9;
    int y = p / 100;
    int x = p - y * 100;
    const float ratios[3] = {0.5f, 1.0f, 2.0f};
    const float scales[3] = {128.f, 256.f, 512.f};
    float ratio = ratios[a / 3];
    float scale = scales[a % 3];
    float h_r = sqrtf(ratio);
    float w_r = 1.0f / h_r;
    float wsz = w_r * scale;
    float hsz = h_r * scale;
    float sx = 16.f * (float)x;
    float sy = 16.f * (float)y;
    float ax1 = sx - wsz * 0.5f;
    float ay1 = sy - hsz * 0.5f;
    float ax2 = sx + wsz * 0.5f;
    float ay2 = sy + hsz * 0.5f;
    float wa = ax2 - ax1;
    float ha = ay2 - ay1;
    float cxa = ax1 + 0.5f * wa;
    float cya = ay1 + 0.5f * ha;
    float dx = regflat[(size_t)idx * 4 + 0];
    float dy = regflat[(size_t)idx * 4 + 1];
    float dw = fminf(regflat[(size_t)idx * 4 + 2], BBOX_CLIP_F);
    float dh = fminf(regflat[(size_t)idx * 4 + 3], BBOX_CLIP_F);
    float cx = dx * wa + cxa;
    float cy = dy * ha + cya;
    float w = expf(dw) * wa;
    float h = expf(dh) * ha;
    float x1 = cx - 0.5f * w, y1 = cy - 0.5f * h, x2 = cx + 0.5f * w, y2 = cy + 0.5f * h;
    x1 = fminf(fmaxf(x1, 0.f), 1600.f);
    y1 = fminf(fmaxf(y1, 0.f), 1600.f);
    x2 = fminf(fmaxf(x2, 0.f), 1600.f);
    y2 = fminf(fmaxf(y2, 0.f), 1600.f);
    boxes[i] = make_float4(x1, y1, x2, y2);
    probv[i] = prob;
    valid[i] = (((x2 - x1) >= 16.f) & ((y2 - y1) >= 16.f)) ? 1u : 0u;
}

// ---------------- NMS suppression bitmask (j > i, iou > 0.7) ----------------
__global__ __launch_bounds__(64) void nms_pairs(const float4* __restrict__ boxes, uint64* __restrict__ sup) {
    int bi = blockIdx.y, bj = blockIdx.x;
    int t = threadIdx.x;
    int i = bi * 64 + t;
    if (bj < bi) { if (i < SUP_ROWS) sup[(size_t)i * NWORDS + bj] = 0; return; }
    __shared__ float4 bx[64];
    __shared__ float ab[64];
    int j0 = bj * 64;
    float4 bb = (j0 + t < PRE_TOPK) ? boxes[j0 + t] : make_float4(0, 0, 0, 0);
    bx[t] = bb;
    ab[t] = (bb.z - bb.x) * (bb.w - bb.y);
    __syncthreads();
    uint64 bits = 0;
    if (i < PRE_TOPK) {
        float4 ba = boxes[i];
        float aa = (ba.z - ba.x) * (ba.w - ba.y);
        for (int jj = 0; jj < 64; ++jj) {
            int j = j0 + jj;
            if (j > i && j < PRE_TOPK) {
                float4 bv = bx[jj];
                float ltx = fmaxf(ba.x, bv.x);
                float lty = fmaxf(ba.y, bv.y);
                float rbx = fminf(ba.z, bv.z);
                float rby = fminf(ba.w, bv.w);
                float wv = fmaxf(rbx - ltx, 0.f);
                float hv = fmaxf(rby - lty, 0.f);
                float inter = wv * hv;
                float iou = inter / (aa + ab[jj] - inter);
                if (iou > 0.7f) bits |= (1ull << jj);
            }
        }
    }
    if (i < SUP_ROWS) sup[(size_t)i * NWORDS + bj] = bits;
}

// ---------------- sequential greedy scan, early-exit at 300 kept ----------------
__global__ __launch_bounds__(64) void nms_scan(const uint32* __restrict__ valid, const uint64* __restrict__ sup,
        uint32* __restrict__ keeplist, uint32* __restrict__ kcount) {
    int l = threadIdx.x;
    __shared__ uint64 srow[64][95];
    uint64 r0 = 0, r1 = 0;
    for (int b = 0; b < 64; ++b) {
        int idx = l * 64 + b;
        if (idx < PRE_TOPK && valid[idx]) r0 |= (1ull << b);
    }
    if (l < NWORDS - 64) {
        int base = (64 + l) * 64;
        for (int b = 0; b < 64; ++b) {
            int idx = base + b;
            if (idx < PRE_TOPK && valid[idx]) r1 |= (1ull << b);
        }
    }
    int outc = 0;
    bool done = false;
    for (int c = 0; c < NWORDS && !done; ++c) {
        __syncthreads();
        for (int rr = 0; rr < 64; ++rr) {
            int row = c * 64 + rr;
            srow[rr][l] = sup[(size_t)row * NWORDS + l];
            if (l < NWORDS - 64) srow[rr][64 + l] = sup[(size_t)row * NWORDS + 64 + l];
        }
        __syncthreads();
        for (int ii = 0; ii < 64; ++ii) {
            int i = c * 64 + ii;
            if (i >= PRE_TOPK) break;
            uint64 kw = (c < 64) ? shfl64(r0, c) : shfl64(r1, c - 64);
            if ((kw >> ii) & 1ull) {
                if (l == 0) keeplist[outc] = (uint32)i;
                ++outc;
                if (outc >= POST_TOPK) { done = true; break; }
                r0 &= ~srow[ii][l];
                if (l < NWORDS - 64) r1 &= ~srow[ii][64 + l];
            }
        }
    }
    if (l == 0) *kcount = (uint32)outc;
}

// ---------------- final gather: first 300 kept ----------------
__global__ __launch_bounds__(512) void finalize_k(const uint32* __restrict__ keeplist, const uint32* __restrict__ kcount,
        const float4* __restrict__ boxes, const float* __restrict__ probv, float* __restrict__ out) {
    int t = threadIdx.x;
    if (t < POST_TOPK) {
        uint32 kc = *kcount;
        if (t < (int)kc) {
            int i = keeplist[t];
            float4 b = boxes[i];
            out[t * 4 + 0] = b.x; out[t * 4 + 1] = b.y; out[t * 4 + 2] = b.z; out[t * 4 + 3] = b.w;
            out[1200 + t] = probv[i];
        } else {
            out[t * 4 + 0] = 0.f; out[t * 4 + 1] = 0.f; out[t * 4 + 2] = 0.f; out[t * 4 + 3] = 0.f;
            out[1200 + t] = 0.f;
        }
    }
}

extern "C" void kernel_launch(void* const* d_in, const int* in_sizes, int n_in,
                              void* d_out, int out_size, void* d_ws, size_t ws_size,
                              hipStream_t stream) {
    const float* fm = (const float*)d_in[1];
    const float* cw = (const float*)d_in[2];
    const float* cb = (const float*)d_in[3];
    const float* ow = (const float*)d_in[4];
    const float* ob = (const float*)d_in[5];
    const float* rw = (const float*)d_in[6];
    const float* rb = (const float*)d_in[7];
    float* out = (float*)d_out;

    uint8_t* base = (uint8_t*)d_ws;
    size_t off = 0;
    auto alloc = [&](size_t bytes) -> void* {
        void* p = base + off;
        off = (off + bytes + 255) & ~(size_t)255;
        return p;
    };
    // --- persistent region ---
    float* feats    = (float*)alloc((size_t)NCH * NPIX * 4);          // 40.96 MB
    uint32* meta    = (uint32*)alloc(64);                             // [0]=T, [1]=cnt
    uint32* keepl   = (uint32*)alloc(POST_TOPK * 4);
    uint32* kcount  = (uint32*)alloc(64);
    // --- union region: W2 (used only by repack_w + conv) overlaps all
    //     post-conv buffers (first written by heads, after conv completes) ---
    size_t ubase = off;
    float* W2       = (float*)alloc((size_t)9 * 1024 * 1024 * 4);     // 36 MB
    size_t endA = off;
    off = ubase;                                                      // rewind: alias
    uint32* keys    = (uint32*)alloc((size_t)NANCH * 4);
    float* regflat  = (float*)alloc((size_t)NANCH * 4 * 4);
    uint64* sel     = (uint64*)alloc((size_t)SORT_N * 8);
    uint64* sorted  = (uint64*)alloc((size_t)PRE_TOPK * 8);
    float4* boxes   = (float4*)alloc((size_t)PRE_TOPK * 16);
    float* probv    = (float*)alloc((size_t)PRE_TOPK * 4);
    uint32* validb  = (uint32*)alloc((size_t)PRE_TOPK * 4);
    uint64* sup     = (uint64*)alloc((size_t)SUP_ROWS * NWORDS * 8);
    size_t endB = off;
    size_t needed = (endA > endB) ? endA : endB;

    if (needed > ws_size) {
        zero_out<<<(out_size + 255) / 256, 256, 0, stream>>>(out, out_size);
        return;
    }

    hipMemsetAsync(meta, 0, 64, stream);

    repack_w<<<dim3(9, 256), 256, 0, stream>>>(cw, W2);
    conv_sw<<<dim3(91, 8), 256, 0, stream>>>(fm, W2, cb, feats);
    heads<<<157, 256, 0, stream>>>(feats, ow, ob, rw, rb, keys, regflat);
    radix_select<<<1, 1024, 0, stream>>>(keys, meta);
    compact_k<<<(NANCH + 255) / 256, 256, 0, stream>>>(keys, meta, meta + 1, sel);
    bitonic_sort<<<1, 1024, 0, stream>>>(meta, sel, sorted);
    decode_k<<<(PRE_TOPK + 255) / 256, 256, 0, stream>>>(sorted, regflat, boxes, probv, validb);
    nms_pairs<<<dim3(NWORDS, NWORDS), 64, 0, stream>>>(boxes, sup);
    nms_scan<<<1, 64, 0, stream>>>(validb, sup, keepl, kcount);
    finalize_k<<<1, 512, 0, stream>>>(keepl, kcount, boxes, probv, out);
}

// Round 4
// 3360.606 us; speedup vs baseline: 1.2450x; 1.1030x over previous
//
#include <hip/hip_runtime.h>
#include <stdint.h>

typedef unsigned int uint32;
typedef unsigned long long uint64;

#define NPIX      10000
#define NCH       1024
#define NANCH     90000
#define PRE_TOPK  6000
#define POST_TOPK 300
#define SORT_N    8192
#define NWORDS    94          // ceil(6000/64)
#define SUP_ROWS  6016
#define BBOX_CLIP_F 4.135166556742356f

// conv geometry
#define TILE_H   8
#define TILE_W   16
#define HALO_H   10
#define HALO_W   18
#define HALO_WP  20          // padded row stride (floats): 2-way bank aliasing only (free)
#define CICHUNK  16
#define C_PER_WAVE 16        // co per wave -> 64 co per 4-wave block -> 1456 blocks

__device__ __forceinline__ uint64 shfl64(uint64 v, int lane) {
    int lo = __shfl((int)(uint32)v, lane);
    int hi = __shfl((int)(uint32)(v >> 32), lane);
    return ((uint64)(uint32)hi << 32) | (uint32)lo;
}

// ---------------- fallback: zero the output (diagnostic clean-fail) ----------------
__global__ __launch_bounds__(256) void zero_out(float* __restrict__ out, int n) {
    int i = blockIdx.x * 256 + threadIdx.x;
    if (i < n) out[i] = 0.f;
}

// ---------------- repack conv_w [co][ci][3][3] -> W3 [cot(64)][ci(1024)][kk(9)][c(16)] ----------------
// Block: 256 thr = 16 ci x 16 c, one (cot, ci_blk) pair; thread reads 9 contiguous kk.
__global__ __launch_bounds__(256) void repack_w3(const float* __restrict__ w, float* __restrict__ W3) {
    int cot = blockIdx.x;             // 0..63
    int cib = blockIdx.y;             // 0..15
    int t = threadIdx.x;
    int c = t & 15;
    int cil = t >> 4;                 // 0..15
    int ci = (cib << 6) | (cil << 2); // 4 ci per thread
    int co = (cot << 4) | c;
#pragma unroll
    for (int r = 0; r < 4; ++r) {
        const float* src = w + ((size_t)co * 1024 + (ci + r)) * 9;
        float* dst = W3 + (((size_t)cot * 1024 + (ci + r)) * 9) * 16 + c;
#pragma unroll
        for (int kk = 0; kk < 9; ++kk)
            dst[kk * 16] = src[kk];
    }
}

// ---------------- 3x3 conv: scalar-weight outer product, 16 co/wave ----------------
// Grid: (91 pixel tiles, 16 co tiles), 256 threads = 4 waves.
// Lane owns 2 pixels (8x8 sub-tile, +8 col offset); wave owns 16 co.
// Per (ci,kk): 1 ds_read2_b32 + 1 s_load_dwordx16 + 32 v_fmac (SGPR weight).
__global__ __launch_bounds__(256) void conv_sw2(const float* __restrict__ fm,
        const float* __restrict__ W3, const float* __restrict__ bias,
        float* __restrict__ feats) {
    __shared__ float xt[CICHUNK][HALO_H][HALO_WP];
    const int t = threadIdx.x;
    const int lane = t & 63;
    const int wv = t >> 6;
    const int tile = blockIdx.x;
    const int tx0 = (tile % 7) * TILE_W;
    const int ty0 = (tile / 7) * TILE_H;
    const int cot = __builtin_amdgcn_readfirstlane((blockIdx.y << 2) + wv);  // 0..63
    const int co0 = cot << 4;
    const int ly = lane >> 3, lx = lane & 7;

    float acc0[C_PER_WAVE] = {};
    float acc1[C_PER_WAVE] = {};

#pragma unroll 1
    for (int c0 = 0; c0 < NCH; c0 += CICHUNK) {
        __syncthreads();
        // stage halo'd fm chunk: CICHUNK x 10 x 18 (zero-padded OOB)
        for (int i = t; i < CICHUNK * HALO_H * HALO_W; i += 256) {
            int ci = i / (HALO_H * HALO_W);
            int rem = i - ci * (HALO_H * HALO_W);
            int hy = rem / HALO_W;
            int hx = rem - hy * HALO_W;
            int gy = ty0 - 1 + hy;
            int gx = tx0 - 1 + hx;
            bool ok = (gy >= 0) & (gy < 100) & (gx >= 0) & (gx < 100);
            xt[ci][hy][hx] = ok ? fm[(size_t)(c0 + ci) * NPIX + gy * 100 + gx] : 0.f;
        }
        __syncthreads();
#pragma unroll 1
        for (int ci = 0; ci < CICHUNK; ++ci) {
            const float* wb = W3 + (((size_t)cot * 1024 + (size_t)(c0 + ci)) * 9) * 16;
#pragma unroll
            for (int kk = 0; kk < 9; ++kk) {
                const int ky = kk / 3, kx2 = kk % 3;
                float x0v = xt[ci][ly + ky][lx + kx2];
                float x1v = xt[ci][ly + ky][lx + 8 + kx2];
#pragma unroll
                for (int c = 0; c < C_PER_WAVE; ++c) {
                    float wgt = wb[kk * 16 + c];   // wave-uniform -> s_load, SGPR operand
                    acc0[c] = fmaf(wgt, x0v, acc0[c]);
                    acc1[c] = fmaf(wgt, x1v, acc1[c]);
                }
            }
        }
    }

    const int gy = ty0 + ly;
    const int gx0 = tx0 + lx;
    const int gx1 = tx0 + 8 + lx;
    const bool oky = gy < 100;
#pragma unroll
    for (int c = 0; c < C_PER_WAVE; ++c) {
        float b = bias[co0 + c];
        if (oky && (gx0 < 100)) feats[(size_t)(co0 + c) * NPIX + gy * 100 + gx0] = fmaxf(acc0[c] + b, 0.f);
        if (oky && (gx1 < 100)) feats[(size_t)(co0 + c) * NPIX + gy * 100 + gx1] = fmaxf(acc1[c] + b, 0.f);
    }
}

// ---------------- 1x1 heads: obj->prob->sortkey, reg->regflat ----------------
__global__ __launch_bounds__(256) void heads(const float* __restrict__ feats,
        const float* __restrict__ objw, const float* __restrict__ objb,
        const float* __restrict__ regw, const float* __restrict__ regb,
        uint32* __restrict__ keys32, float* __restrict__ regflat) {
    int p0 = blockIdx.x << 6;
    int t = threadIdx.x;
    int pl = t & 63;
    int g = t >> 6;     // 0..3
    __shared__ float fts[64][65];
    __shared__ float wl[48][64];
    float acc[12] = {};
    for (int c0 = 0; c0 < 1024; c0 += 64) {
        __syncthreads();
#pragma unroll
        for (int r = 0; r < 16; ++r) {
            int cc = g + (r << 2);
            int p = p0 + pl;
            fts[cc][pl] = (p < NPIX) ? feats[(size_t)(c0 + cc) * NPIX + p] : 0.f;
        }
#pragma unroll
        for (int i = 0; i < 12; ++i) {
            int flat = (i << 8) + t;     // < 3072
            int o = flat >> 6;
            int cc = flat & 63;
            float v = 0.f;
            if (o < 9) v = objw[o * 1024 + c0 + cc];
            else if (o < 45) v = regw[(o - 9) * 1024 + c0 + cc];
            wl[o][cc] = v;
        }
        __syncthreads();
#pragma unroll 16
        for (int cc = 0; cc < 64; ++cc) {
            float v = fts[cc][pl];
#pragma unroll
            for (int i = 0; i < 12; ++i)
                acc[i] = fmaf(v, wl[g + (i << 2)][cc], acc[i]);
        }
    }
    int p = p0 + pl;
    if (p < NPIX) {
#pragma unroll
        for (int i = 0; i < 12; ++i) {
            int o = g + (i << 2);
            if (o < 9) {
                float logit = acc[i] + objb[o];
                float prob = 1.f / (1.f + expf(-logit));
                keys32[p * 9 + o] = 0xFFFFFFFFu - __float_as_uint(prob);
            } else if (o < 45) {
                int ch = o - 9;
                float v = acc[i] + regb[ch];
                int a = ch >> 2, d = ch & 3;
                regflat[((size_t)p * 9 + a) * 4 + d] = v;
            }
        }
    }
}

// ---------------- radix select: T = 6000th smallest key ----------------
__global__ __launch_bounds__(1024) void radix_select(const uint32* __restrict__ keys, uint32* __restrict__ meta) {
    __shared__ uint32 hist[256];
    __shared__ uint32 sPrefix, sK;
    int t = threadIdx.x;
    if (t == 0) { sPrefix = 0; sK = PRE_TOPK; }
    for (int pass = 0; pass < 4; ++pass) {
        int shift = 24 - pass * 8;
        uint32 kmask = pass ? (0xFFFFFFFFu << (32 - 8 * pass)) : 0u;
        if (t < 256) hist[t] = 0;
        __syncthreads();
        uint32 pref = sPrefix;
        for (int i = t; i < NANCH; i += 1024) {
            uint32 k = keys[i];
            if ((k & kmask) == pref) atomicAdd(&hist[(k >> shift) & 255], 1u);
        }
        __syncthreads();
        if (t == 0) {
            uint32 cum = 0, K = sK;
            for (int b = 0; b < 256; ++b) {
                uint32 c = hist[b];
                if (cum + c >= K) { sPrefix = pref | ((uint32)b << shift); sK = K - cum; break; }
                cum += c;
            }
        }
        __syncthreads();
    }
    if (t == 0) meta[0] = sPrefix;
}

// ---------------- compact all keys <= T ----------------
__global__ __launch_bounds__(256) void compact_k(const uint32* __restrict__ keys, const uint32* __restrict__ meta,
        uint32* __restrict__ cnt, uint64* __restrict__ sel) {
    int i = blockIdx.x * 256 + threadIdx.x;
    if (i >= NANCH) return;
    uint32 T = meta[0];
    uint32 k = keys[i];
    if (k <= T) {
        uint32 pos = atomicAdd(cnt, 1u);
        if (pos < SORT_N) sel[pos] = ((uint64)k << 32) | (uint32)i;
    }
}

// ---------------- single-block bitonic sort of 8192 (key32|idx) ----------------
__global__ __launch_bounds__(1024) void bitonic_sort(const uint32* __restrict__ meta, const uint64* __restrict__ sel,
        uint64* __restrict__ sorted) {
    __shared__ uint64 arr[SORT_N];
    int t = threadIdx.x;
    uint32 cnt = meta[1]; if (cnt > SORT_N) cnt = SORT_N;
    for (int i = t; i < SORT_N; i += 1024) arr[i] = (i < (int)cnt) ? sel[i] : 0xFFFFFFFFFFFFFFFFull;
    __syncthreads();
    for (unsigned k = 2; k <= SORT_N; k <<= 1) {
        for (unsigned j = k >> 1; j > 0; j >>= 1) {
#pragma unroll 1
            for (int s = 0; s < SORT_N / 1024; ++s) {
                unsigned i = s * 1024 + t;
                unsigned l = i ^ j;
                if (l > i) {
                    uint64 a = arr[i], b = arr[l];
                    bool up = ((i & k) == 0);
                    if ((a > b) == up) { arr[i] = b; arr[l] = a; }
                }
            }
            __syncthreads();
        }
    }
    for (int i = t; i < PRE_TOPK; i += 1024) sorted[i] = arr[i];
}

// ---------------- decode + clip + min-size for top 6000 ----------------
__global__ __launch_bounds__(256) void decode_k(const uint64* __restrict__ sorted,
        const float* __restrict__ regflat,
        float4* __restrict__ boxes, float* __restrict__ probv, uint32* __restrict__ valid) {
    int i = blockIdx.x * 256 + threadIdx.x;
    if (i >= PRE_TOPK) return;
    uint64 v = sorted[i];
    uint32 idx = (uint32)v;
    uint32 key = (uint32)(v >> 32);
    float prob = __uint_as_float(0xFFFFFFFFu - key);
    int a = idx % 9;
    int p = idx / 9;
    int y = p / 100;
    int x = p - y * 100;
    const float ratios[3] = {0.5f, 1.0f, 2.0f};
    const float scales[3] = {128.f, 256.f, 512.f};
    float ratio = ratios[a / 3];
    float scale = scales[a % 3];
    float h_r = sqrtf(ratio);
    float w_r = 1.0f / h_r;
    float wsz = w_r * scale;
    float hsz = h_r * scale;
    float sx = 16.f * (float)x;
    float sy = 16.f * (float)y;
    float ax1 = sx - wsz * 0.5f;
    float ay1 = sy - hsz * 0.5f;
    float ax2 = sx + wsz * 0.5f;
    float ay2 = sy + hsz * 0.5f;
    float wa = ax2 - ax1;
    float ha = ay2 - ay1;
    float cxa = ax1 + 0.5f * wa;
    float cya = ay1 + 0.5f * ha;
    float dx = regflat[(size_t)idx * 4 + 0];
    float dy = regflat[(size_t)idx * 4 + 1];
    float dw = fminf(regflat[(size_t)idx * 4 + 2], BBOX_CLIP_F);
    float dh = fminf(regflat[(size_t)idx * 4 + 3], BBOX_CLIP_F);
    float cx = dx * wa + cxa;
    float cy = dy * ha + cya;
    float w = expf(dw) * wa;
    float h = expf(dh) * ha;
    float x1 = cx - 0.5f * w, y1 = cy - 0.5f * h, x2 = cx + 0.5f * w, y2 = cy + 0.5f * h;
    x1 = fminf(fmaxf(x1, 0.f), 1600.f);
    y1 = fminf(fmaxf(y1, 0.f), 1600.f);
    x2 = fminf(fmaxf(x2, 0.f), 1600.f);
    y2 = fminf(fmaxf(y2, 0.f), 1600.f);
    boxes[i] = make_float4(x1, y1, x2, y2);
    probv[i] = prob;
    valid[i] = (((x2 - x1) >= 16.f) & ((y2 - y1) >= 16.f)) ? 1u : 0u;
}

// ---------------- NMS suppression bitmask (j > i, iou > 0.7) ----------------
__global__ __launch_bounds__(64) void nms_pairs(const float4* __restrict__ boxes, uint64* __restrict__ sup) {
    int bi = blockIdx.y, bj = blockIdx.x;
    int t = threadIdx.x;
    int i = bi * 64 + t;
    if (bj < bi) { if (i < SUP_ROWS) sup[(size_t)i * NWORDS + bj] = 0; return; }
    __shared__ float4 bx[64];
    __shared__ float ab[64];
    int j0 = bj * 64;
    float4 bb = (j0 + t < PRE_TOPK) ? boxes[j0 + t] : make_float4(0, 0, 0, 0);
    bx[t] = bb;
    ab[t] = (bb.z - bb.x) * (bb.w - bb.y);
    __syncthreads();
    uint64 bits = 0;
    if (i < PRE_TOPK) {
        float4 ba = boxes[i];
        float aa = (ba.z - ba.x) * (ba.w - ba.y);
        for (int jj = 0; jj < 64; ++jj) {
            int j = j0 + jj;
            if (j > i && j < PRE_TOPK) {
                float4 bv = bx[jj];
                float ltx = fmaxf(ba.x, bv.x);
                float lty = fmaxf(ba.y, bv.y);
                float rbx = fminf(ba.z, bv.z);
                float rby = fminf(ba.w, bv.w);
                float wv = fmaxf(rbx - ltx, 0.f);
                float hv = fmaxf(rby - lty, 0.f);
                float inter = wv * hv;
                float iou = inter / (aa + ab[jj] - inter);
                if (iou > 0.7f) bits |= (1ull << jj);
            }
        }
    }
    if (i < SUP_ROWS) sup[(size_t)i * NWORDS + bj] = bits;
}

// ---------------- sequential greedy scan, early-exit at 300 kept ----------------
__global__ __launch_bounds__(64) void nms_scan(const uint32* __restrict__ valid, const uint64* __restrict__ sup,
        uint32* __restrict__ keeplist, uint32* __restrict__ kcount) {
    int l = threadIdx.x;
    __shared__ uint64 srow[64][95];
    uint64 r0 = 0, r1 = 0;
    for (int b = 0; b < 64; ++b) {
        int idx = l * 64 + b;
        if (idx < PRE_TOPK && valid[idx]) r0 |= (1ull << b);
    }
    if (l < NWORDS - 64) {
        int base = (64 + l) * 64;
        for (int b = 0; b < 64; ++b) {
            int idx = base + b;
            if (idx < PRE_TOPK && valid[idx]) r1 |= (1ull << b);
        }
    }
    int outc = 0;
    bool done = false;
    for (int c = 0; c < NWORDS && !done; ++c) {
        __syncthreads();
        for (int rr = 0; rr < 64; ++rr) {
            int row = c * 64 + rr;
            srow[rr][l] = sup[(size_t)row * NWORDS + l];
            if (l < NWORDS - 64) srow[rr][64 + l] = sup[(size_t)row * NWORDS + 64 + l];
        }
        __syncthreads();
        for (int ii = 0; ii < 64; ++ii) {
            int i = c * 64 + ii;
            if (i >= PRE_TOPK) break;
            uint64 kw = (c < 64) ? shfl64(r0, c) : shfl64(r1, c - 64);
            if ((kw >> ii) & 1ull) {
                if (l == 0) keeplist[outc] = (uint32)i;
                ++outc;
                if (outc >= POST_TOPK) { done = true; break; }
                r0 &= ~srow[ii][l];
                if (l < NWORDS - 64) r1 &= ~srow[ii][64 + l];
            }
        }
    }
    if (l == 0) *kcount = (uint32)outc;
}

// ---------------- final gather: first 300 kept ----------------
__global__ __launch_bounds__(512) void finalize_k(const uint32* __restrict__ keeplist, const uint32* __restrict__ kcount,
        const float4* __restrict__ boxes, const float* __restrict__ probv, float* __restrict__ out) {
    int t = threadIdx.x;
    if (t < POST_TOPK) {
        uint32 kc = *kcount;
        if (t < (int)kc) {
            int i = keeplist[t];
            float4 b = boxes[i];
            out[t * 4 + 0] = b.x; out[t * 4 + 1] = b.y; out[t * 4 + 2] = b.z; out[t * 4 + 3] = b.w;
            out[1200 + t] = probv[i];
        } else {
            out[t * 4 + 0] = 0.f; out[t * 4 + 1] = 0.f; out[t * 4 + 2] = 0.f; out[t * 4 + 3] = 0.f;
            out[1200 + t] = 0.f;
        }
    }
}

extern "C" void kernel_launch(void* const* d_in, const int* in_sizes, int n_in,
                              void* d_out, int out_size, void* d_ws, size_t ws_size,
                              hipStream_t stream) {
    const float* fm = (const float*)d_in[1];
    const float* cw = (const float*)d_in[2];
    const float* cb = (const float*)d_in[3];
    const float* ow = (const float*)d_in[4];
    const float* ob = (const float*)d_in[5];
    const float* rw = (const float*)d_in[6];
    const float* rb = (const float*)d_in[7];
    float* out = (float*)d_out;

    uint8_t* base = (uint8_t*)d_ws;
    size_t off = 0;
    auto alloc = [&](size_t bytes) -> void* {
        void* p = base + off;
        off = (off + bytes + 255) & ~(size_t)255;
        return p;
    };
    // --- persistent region ---
    float* feats    = (float*)alloc((size_t)NCH * NPIX * 4);          // 40.96 MB
    uint32* meta    = (uint32*)alloc(64);                             // [0]=T, [1]=cnt
    uint32* keepl   = (uint32*)alloc(POST_TOPK * 4);
    uint32* kcount  = (uint32*)alloc(64);
    // --- union region: W3 (used only by repack_w3 + conv) overlaps all
    //     post-conv buffers (first written by heads, after conv completes) ---
    size_t ubase = off;
    float* W3       = (float*)alloc((size_t)64 * 1024 * 9 * 16 * 4);  // 36.9 MB
    size_t endA = off;
    off = ubase;                                                      // rewind: alias
    uint32* keys    = (uint32*)alloc((size_t)NANCH * 4);
    float* regflat  = (float*)alloc((size_t)NANCH * 4 * 4);
    uint64* sel     = (uint64*)alloc((size_t)SORT_N * 8);
    uint64* sorted  = (uint64*)alloc((size_t)PRE_TOPK * 8);
    float4* boxes   = (float4*)alloc((size_t)PRE_TOPK * 16);
    float* probv    = (float*)alloc((size_t)PRE_TOPK * 4);
    uint32* validb  = (uint32*)alloc((size_t)PRE_TOPK * 4);
    uint64* sup     = (uint64*)alloc((size_t)SUP_ROWS * NWORDS * 8);
    size_t endB = off;
    size_t needed = (endA > endB) ? endA : endB;

    if (needed > ws_size) {
        zero_out<<<(out_size + 255) / 256, 256, 0, stream>>>(out, out_size);
        return;
    }

    hipMemsetAsync(meta, 0, 64, stream);

    repack_w3<<<dim3(64, 16), 256, 0, stream>>>(cw, W3);
    conv_sw2<<<dim3(91, 16), 256, 0, stream>>>(fm, W3, cb, feats);
    heads<<<157, 256, 0, stream>>>(feats, ow, ob, rw, rb, keys, regflat);
    radix_select<<<1, 1024, 0, stream>>>(keys, meta);
    compact_k<<<(NANCH + 255) / 256, 256, 0, stream>>>(keys, meta, meta + 1, sel);
    bitonic_sort<<<1, 1024, 0, stream>>>(meta, sel, sorted);
    decode_k<<<(PRE_TOPK + 255) / 256, 256, 0, stream>>>(sorted, regflat, boxes, probv, validb);
    nms_pairs<<<dim3(NWORDS, NWORDS), 64, 0, stream>>>(boxes, sup);
    nms_scan<<<1, 64, 0, stream>>>(validb, sup, keepl, kcount);
    finalize_k<<<1, 512, 0, stream>>>(keepl, kcount, boxes, probv, out);
}